// Round 1
// baseline (373.801 us; speedup 1.0000x reference)
//
#include <hip/hip_runtime.h>
#include <hip/hip_bf16.h>
#include <math.h>

#define B_ 8
#define N_ 1024
#define C_ 768
#define H_ 8
#define HD_ 96
#define DFF_ 3072
#define SCALE_ 0.10206207261596575f  // 1/sqrt(96)

typedef __attribute__((ext_vector_type(8))) short bf16x8;
typedef __attribute__((ext_vector_type(4))) float f32x4;
typedef __attribute__((ext_vector_type(4))) short sh4;

__device__ __forceinline__ short f2bf(float f){
  __hip_bfloat16 h = __float2bfloat16(f);
  return __builtin_bit_cast(short, h);
}
__device__ __forceinline__ float bf2f(short s){
  unsigned u = ((unsigned)(unsigned short)s) << 16;
  return __builtin_bit_cast(float, u);
}
#define MFMA16(a,b,c) __builtin_amdgcn_mfma_f32_16x16x32_bf16((a),(b),(c),0,0,0)

// ---------------- conv 3x3 SAME on 16x16x3 patches -> q bf16 [B,N,C] --------
__global__ void conv_q_kernel(const float* __restrict__ x, const float* __restrict__ w,
                              short* __restrict__ qb){
  int p = blockIdx.x;          // patch index: 0 .. B*N-1
  int t = threadIdx.x;         // 256
  __shared__ float xs[768];
  __shared__ float ws[81];
  const float* xp = x + (size_t)p * 768;
  xs[t] = xp[t]; xs[t+256] = xp[t+256]; xs[t+512] = xp[t+512];
  if (t < 81) ws[t] = w[t];
  __syncthreads();
  int i = t >> 4, j = t & 15;
  float a0=0.f, a1=0.f, a2=0.f;
  #pragma unroll
  for (int di=0; di<3; ++di){
    int ii = i + di - 1;
    if (ii < 0 || ii > 15) continue;
    #pragma unroll
    for (int dj=0; dj<3; ++dj){
      int jj = j + dj - 1;
      if (jj < 0 || jj > 15) continue;
      const float* cell = &xs[(ii*16+jj)*3];
      const float* wp = &ws[(di*3+dj)*9];
      #pragma unroll
      for (int ci=0; ci<3; ++ci){
        float xv = cell[ci];
        a0 += xv * wp[ci*3+0];
        a1 += xv * wp[ci*3+1];
        a2 += xv * wp[ci*3+2];
      }
    }
  }
  short* qp = qb + (size_t)p*768 + t*3;
  qp[0]=f2bf(a0); qp[1]=f2bf(a1); qp[2]=f2bf(a2);
}

// ---------------- q [B,N,C] bf16 -> Vt [B,C,N] bf16 -------------------------
__global__ void vt_kernel(const short* __restrict__ in, short* __restrict__ out){
  __shared__ short tile[32][33];
  int b = blockIdx.z;
  int c0 = blockIdx.x*32, n0 = blockIdx.y*32;
  int t = threadIdx.x;
  const short* ib = in + (size_t)b*N_*C_;
  short* ob = out + (size_t)b*C_*N_;
  #pragma unroll
  for (int i=0;i<4;i++){
    int idx = i*256+t; int r = idx>>5, cc = idx&31;
    tile[r][cc] = ib[(size_t)(n0+r)*C_ + c0+cc];
  }
  __syncthreads();
  #pragma unroll
  for (int i=0;i<4;i++){
    int idx = i*256+t; int r = idx>>5, cc = idx&31;
    ob[(size_t)(c0+r)*N_ + n0+cc] = tile[cc][r];
  }
}

// ---------------- W [K,Nn] f32 -> Wt [Nn,K] bf16 ----------------------------
__global__ void wtrans_kernel(const float* __restrict__ in, short* __restrict__ out,
                              int K, int Nn){
  __shared__ float tile[32][33];
  int n0 = blockIdx.x*32, k0 = blockIdx.y*32;
  int t = threadIdx.x;
  #pragma unroll
  for (int i=0;i<4;i++){
    int idx=i*256+t; int r=idx>>5, cc=idx&31;
    tile[r][cc] = in[(size_t)(k0+r)*Nn + n0+cc];
  }
  __syncthreads();
  #pragma unroll
  for (int i=0;i<4;i++){
    int idx=i*256+t; int r=idx>>5, cc=idx&31;
    out[(size_t)(n0+r)*K + k0+cc] = f2bf(tile[cc][r]);
  }
}

// ---------------- fused attention: softmax + re-attention + PV --------------
// grid 256 = B * (N/32); 512 threads = 8 waves = 8 heads; each WG: 32 q-rows.
__global__ __launch_bounds__(512, 2)
void attn_kernel(const short* __restrict__ qb, const short* __restrict__ vt,
                 const float* __restrict__ rw, const float* __restrict__ rb,
                 const float* __restrict__ bng, const float* __restrict__ bnb,
                 short* __restrict__ out)
{
  __shared__ short P_lds[8][32][72];   // [head][n-row][m-col], padded
  int b = blockIdx.x >> 5;
  int n0 = (blockIdx.x & 31) * 32;
  int tid = threadIdx.x;
  int w = tid >> 6;                    // wave == head
  int l = tid & 63;
  int lg = l >> 4, lr = l & 15;
  const short* qbase = qb + (size_t)b*N_*C_;
  const short* vbase = vt + (size_t)b*C_*N_;

  // Q fragments for this wave's 32 rows, own head slice (hd=96 = 3 k-chunks)
  bf16x8 qf[2][3];
  #pragma unroll
  for (int a=0;a<2;++a)
    #pragma unroll
    for (int kc=0;kc<3;++kc)
      qf[a][kc] = *(const bf16x8*)(qbase + (size_t)(n0+a*16+lr)*C_ + w*HD_ + kc*32 + lg*8);

  // re-attention mixing weights folded with BN scale
  float bns = bng[w] * rsqrtf(1.0f + 1e-3f);
  float wmix[8];
  #pragma unroll
  for (int h=0;h<8;++h) wmix[h] = rw[w*8+h] * bns;
  float cw = rb[w]*bns + bnb[w];

  float mrun[2][4], lrun[2][4];
  #pragma unroll
  for (int a=0;a<2;++a)
    #pragma unroll
    for (int r=0;r<4;++r){ mrun[a][r] = -1e30f; lrun[a][r] = 0.f; }

  // ---- pass 1: exact softmax row stats (online max / sumexp) ----
  for (int mt=0; mt<16; ++mt){
    int m0 = mt*64;
    f32x4 sacc[2][4];
    #pragma unroll
    for (int a=0;a<2;++a)
      #pragma unroll
      for (int nt=0;nt<4;++nt) sacc[a][nt] = (f32x4){0.f,0.f,0.f,0.f};
    #pragma unroll
    for (int nt=0;nt<4;++nt){
      bf16x8 kf[3];
      #pragma unroll
      for (int kc=0;kc<3;++kc)
        kf[kc] = *(const bf16x8*)(qbase + (size_t)(m0+nt*16+lr)*C_ + w*HD_ + kc*32 + lg*8);
      #pragma unroll
      for (int kc=0;kc<3;++kc){
        sacc[0][nt] = MFMA16(qf[0][kc], kf[kc], sacc[0][nt]);
        sacc[1][nt] = MFMA16(qf[1][kc], kf[kc], sacc[1][nt]);
      }
    }
    #pragma unroll
    for (int a=0;a<2;++a){
      #pragma unroll
      for (int r=0;r<4;++r){
        float tm = fmaxf(fmaxf(sacc[a][0][r], sacc[a][1][r]),
                         fmaxf(sacc[a][2][r], sacc[a][3][r]));
        #pragma unroll
        for (int off=1; off<16; off<<=1) tm = fmaxf(tm, __shfl_xor(tm, off));
        tm *= SCALE_;
        float mn = fmaxf(mrun[a][r], tm);
        float s = 0.f;
        #pragma unroll
        for (int nt=0;nt<4;++nt) s += __expf(sacc[a][nt][r]*SCALE_ - mn);
        #pragma unroll
        for (int off=1; off<16; off<<=1) s += __shfl_xor(s, off);
        lrun[a][r] = lrun[a][r]*__expf(mrun[a][r]-mn) + s;
        mrun[a][r] = mn;
      }
    }
  }
  float invl[2][4];
  #pragma unroll
  for (int a=0;a<2;++a)
    #pragma unroll
    for (int r=0;r<4;++r) invl[a][r] = 1.0f / lrun[a][r];

  // ---- pass 2: recompute S, normalize, mix heads, PV ----
  f32x4 oacc[2][6];
  #pragma unroll
  for (int a=0;a<2;++a)
    #pragma unroll
    for (int nt=0;nt<6;++nt) oacc[a][nt] = (f32x4){0.f,0.f,0.f,0.f};

  for (int mt=0; mt<16; ++mt){
    int m0 = mt*64;
    f32x4 sacc[2][4];
    #pragma unroll
    for (int a=0;a<2;++a)
      #pragma unroll
      for (int nt=0;nt<4;++nt) sacc[a][nt] = (f32x4){0.f,0.f,0.f,0.f};
    #pragma unroll
    for (int nt=0;nt<4;++nt){
      bf16x8 kf[3];
      #pragma unroll
      for (int kc=0;kc<3;++kc)
        kf[kc] = *(const bf16x8*)(qbase + (size_t)(m0+nt*16+lr)*C_ + w*HD_ + kc*32 + lg*8);
      #pragma unroll
      for (int kc=0;kc<3;++kc){
        sacc[0][nt] = MFMA16(qf[0][kc], kf[kc], sacc[0][nt]);
        sacc[1][nt] = MFMA16(qf[1][kc], kf[kc], sacc[1][nt]);
      }
    }
    __syncthreads();   // previous iteration's P reads complete
    #pragma unroll
    for (int a=0;a<2;++a)
      #pragma unroll
      for (int nt=0;nt<4;++nt)
        #pragma unroll
        for (int r=0;r<4;++r){
          float p = __expf(sacc[a][nt][r]*SCALE_ - mrun[a][r]) * invl[a][r];
          P_lds[w][a*16 + lg*4 + r][nt*16 + lr] = f2bf(p);
        }
    __syncthreads();   // all heads' P visible
    #pragma unroll
    for (int kc=0;kc<2;++kc){
      bf16x8 amix[2];
      #pragma unroll
      for (int a=0;a<2;++a){
        float pm[8];
        #pragma unroll
        for (int j=0;j<8;++j) pm[j] = cw;
        #pragma unroll
        for (int h=0;h<8;++h){
          bf16x8 ph = *(const bf16x8*)&P_lds[h][a*16+lr][kc*32+lg*8];
          #pragma unroll
          for (int j=0;j<8;++j) pm[j] += wmix[h]*bf2f(ph[j]);
        }
        #pragma unroll
        for (int j=0;j<8;++j) amix[a][j] = f2bf(pm[j]);
      }
      bf16x8 vf[6];
      #pragma unroll
      for (int nt=0;nt<6;++nt)
        vf[nt] = *(const bf16x8*)(vbase + (size_t)(w*HD_+nt*16+lr)*N_ + m0 + kc*32 + lg*8);
      #pragma unroll
      for (int nt=0;nt<6;++nt){
        oacc[0][nt] = MFMA16(amix[0], vf[nt], oacc[0][nt]);
        oacc[1][nt] = MFMA16(amix[1], vf[nt], oacc[1][nt]);
      }
    }
  }
  short* obase = out + (size_t)b*N_*C_;
  #pragma unroll
  for (int a=0;a<2;++a)
    #pragma unroll
    for (int nt=0;nt<6;++nt)
      #pragma unroll
      for (int r=0;r<4;++r)
        obase[(size_t)(n0 + a*16 + lg*4 + r)*C_ + w*HD_ + nt*16 + lr] = f2bf(oacc[a][nt][r]);
}

// ---------------- BT-GEMM 128x128, BK=64, reg-staged double buffer ----------
// C[M,Nn] = A[M,K](bf16) * Bt[Nn,K]^T(bf16); EPI 0: +bias+res -> f32
//                                            EPI 1: +bias, exact GELU -> bf16
template<int EPI>
__global__ __launch_bounds__(256, 3)
void gemm_bt_kernel(const short* __restrict__ A, const short* __restrict__ Bt,
                    const float* __restrict__ bias, const float* __restrict__ res,
                    float* __restrict__ Of, short* __restrict__ Ob,
                    int M, int Nn, int K)
{
  __shared__ short As[128*72];
  __shared__ short Bs[128*72];
  int gm = blockIdx.y*128, gn = blockIdx.x*128;
  int tid = threadIdx.x;
  int w = tid>>6, l = tid&63, lg = l>>4, lr = l&15;
  int wr = w>>1, wc = w&1;
  f32x4 acc[4][4];
  #pragma unroll
  for (int mt=0;mt<4;++mt)
    #pragma unroll
    for (int nt=0;nt<4;++nt) acc[mt][nt] = (f32x4){0.f,0.f,0.f,0.f};

  bf16x8 ra[4], rbv[4];
  #pragma unroll
  for (int i=0;i<4;i++){
    int c = i*256+tid; int row = c>>3, cc = c&7;
    ra[i]  = *(const bf16x8*)(A  + (size_t)(gm+row)*K + cc*8);
    rbv[i] = *(const bf16x8*)(Bt + (size_t)(gn+row)*K + cc*8);
  }
  for (int kb=0; kb<K; kb+=64){
    __syncthreads();
    #pragma unroll
    for (int i=0;i<4;i++){
      int c = i*256+tid; int row=c>>3, cc=c&7;
      *(bf16x8*)&As[row*72 + cc*8] = ra[i];
      *(bf16x8*)&Bs[row*72 + cc*8] = rbv[i];
    }
    __syncthreads();
    if (kb + 64 < K){
      #pragma unroll
      for (int i=0;i<4;i++){
        int c=i*256+tid; int row=c>>3, cc=c&7;
        ra[i]  = *(const bf16x8*)(A  + (size_t)(gm+row)*K + kb+64 + cc*8);
        rbv[i] = *(const bf16x8*)(Bt + (size_t)(gn+row)*K + kb+64 + cc*8);
      }
    }
    #pragma unroll
    for (int kc=0;kc<2;++kc){
      bf16x8 af[4], bfr[4];
      #pragma unroll
      for (int mt=0;mt<4;++mt)
        af[mt] = *(const bf16x8*)&As[(wr*64+mt*16+lr)*72 + kc*32 + lg*8];
      #pragma unroll
      for (int nt=0;nt<4;++nt)
        bfr[nt] = *(const bf16x8*)&Bs[(wc*64+nt*16+lr)*72 + kc*32 + lg*8];
      #pragma unroll
      for (int mt=0;mt<4;++mt)
        #pragma unroll
        for (int nt=0;nt<4;++nt)
          acc[mt][nt] = MFMA16(af[mt], bfr[nt], acc[mt][nt]);
    }
  }
  #pragma unroll
  for (int mt=0;mt<4;++mt){
    #pragma unroll
    for (int nt=0;nt<4;++nt){
      #pragma unroll
      for (int r=0;r<4;++r){
        int row = gm + wr*64 + mt*16 + lg*4 + r;
        int col = gn + wc*64 + nt*16 + lr;
        float v = acc[mt][nt][r] + bias[col];
        if (EPI == 0){
          v += res[(size_t)row*Nn + col];
          Of[(size_t)row*Nn + col] = v;
        } else {
          v = 0.5f*v*(1.0f + erff(v*0.70710678118654752f));
          Ob[(size_t)row*Nn + col] = f2bf(v);
        }
      }
    }
  }
}

// ---------------- LayerNorm over 768, 1 wave per row ------------------------
template<int WB>
__global__ void ln_kernel(const float* __restrict__ in, const float* __restrict__ gam,
                          const float* __restrict__ bet, float* __restrict__ of,
                          short* __restrict__ ob)
{
  int row = blockIdx.x*4 + (threadIdx.x>>6);
  int l = threadIdx.x & 63;
  const float* ip = in + (size_t)row*C_;
  float v[12];
  #pragma unroll
  for (int i=0;i<3;i++) *(float4*)&v[i*4] = *(const float4*)(ip + i*256 + l*4);
  float s = 0.f;
  #pragma unroll
  for (int i=0;i<12;i++) s += v[i];
  #pragma unroll
  for (int off=1; off<64; off<<=1) s += __shfl_xor(s, off);
  float mu = s * (1.0f/768.0f);
  float q = 0.f;
  #pragma unroll
  for (int i=0;i<12;i++){ float d = v[i]-mu; q += d*d; }
  #pragma unroll
  for (int off=1; off<64; off<<=1) q += __shfl_xor(q, off);
  float rstd = rsqrtf(q*(1.0f/768.0f) + 1e-3f);
  #pragma unroll
  for (int i=0;i<3;i++){
    float4 gv = *(const float4*)(gam + i*256 + l*4);
    float4 bv = *(const float4*)(bet + i*256 + l*4);
    float o0 = (v[i*4+0]-mu)*rstd*gv.x + bv.x;
    float o1 = (v[i*4+1]-mu)*rstd*gv.y + bv.y;
    float o2 = (v[i*4+2]-mu)*rstd*gv.z + bv.z;
    float o3 = (v[i*4+3]-mu)*rstd*gv.w + bv.w;
    float4 ov = {o0,o1,o2,o3};
    *(float4*)(of + (size_t)row*C_ + i*256 + l*4) = ov;
    if (WB){
      sh4 obv = { f2bf(o0), f2bf(o1), f2bf(o2), f2bf(o3) };
      *(sh4*)(ob + (size_t)row*C_ + i*256 + l*4) = obv;
    }
  }
}

extern "C" void kernel_launch(void* const* d_in, const int* in_sizes, int n_in,
                              void* d_out, int out_size, void* d_ws, size_t ws_size,
                              hipStream_t stream)
{
  const float* enc       = (const float*)d_in[0];
  const float* qconv_w   = (const float*)d_in[1];
  const float* reatten_w = (const float*)d_in[2];
  const float* reatten_b = (const float*)d_in[3];
  const float* bn_gamma  = (const float*)d_in[4];
  const float* bn_beta   = (const float*)d_in[5];
  const float* proj_w    = (const float*)d_in[6];
  const float* proj_b    = (const float*)d_in[7];
  const float* ffn_w1    = (const float*)d_in[8];
  const float* ffn_b1    = (const float*)d_in[9];
  const float* ffn_w2    = (const float*)d_in[10];
  const float* ffn_b2    = (const float*)d_in[11];
  const float* ln1_g     = (const float*)d_in[12];
  const float* ln1_b     = (const float*)d_in[13];
  const float* ln2_g     = (const float*)d_in[14];
  const float* ln2_b     = (const float*)d_in[15];
  float* outp = (float*)d_out;

  char* ws = (char*)d_ws;
  short* qbuf  = (short*)(ws);                         // 12.6 MB  q bf16 [B,N,C]
  short* vtbuf = (short*)(ws + 12582912);              // 12.6 MB  Vt bf16 [B,C,N]
  short* atbuf = (short*)(ws + 25165824);              // 12.6 MB  attn out bf16
  float* ypre  = (float*)(ws + 37748736);              // 25.2 MB  pre-LN f32 (reused)
  float* x1    = (float*)(ws + 62914560);              // 25.2 MB  LN1 out f32
  short* x1b   = (short*)(ws + 88080384);              // 12.6 MB  LN1 out bf16
  short* hbuf  = (short*)(ws + 100663296);             // 50.3 MB  FFN hidden bf16
  short* wpt   = (short*)(ws + 150994944);             // 1.2 MB   proj_w^T bf16
  short* w1t   = (short*)(ws + 152174592);             // 4.7 MB   ffn_w1^T bf16
  short* w2t   = (short*)(ws + 156893184);             // 4.7 MB   ffn_w2^T bf16

  conv_q_kernel<<<B_*N_, 256, 0, stream>>>(enc, qconv_w, qbuf);
  vt_kernel<<<dim3(C_/32, N_/32, B_), 256, 0, stream>>>(qbuf, vtbuf);
  wtrans_kernel<<<dim3(C_/32,  C_/32), 256, 0, stream>>>(proj_w, wpt, C_,  C_);
  wtrans_kernel<<<dim3(DFF_/32, C_/32), 256, 0, stream>>>(ffn_w1, w1t, C_,  DFF_);
  wtrans_kernel<<<dim3(C_/32, DFF_/32), 256, 0, stream>>>(ffn_w2, w2t, DFF_, C_);
  attn_kernel<<<B_*(N_/32), 512, 0, stream>>>(qbuf, vtbuf, reatten_w, reatten_b,
                                              bn_gamma, bn_beta, atbuf);
  gemm_bt_kernel<0><<<dim3(C_/128, (B_*N_)/128), 256, 0, stream>>>(
      atbuf, wpt, proj_b, enc, ypre, nullptr, B_*N_, C_, C_);
  ln_kernel<1><<<(B_*N_)/4, 256, 0, stream>>>(ypre, ln1_g, ln1_b, x1, x1b);
  gemm_bt_kernel<1><<<dim3(DFF_/128, (B_*N_)/128), 256, 0, stream>>>(
      x1b, w1t, ffn_b1, nullptr, nullptr, hbuf, B_*N_, DFF_, C_);
  gemm_bt_kernel<0><<<dim3(C_/128, (B_*N_)/128), 256, 0, stream>>>(
      hbuf, w2t, ffn_b2, x1, ypre, nullptr, B_*N_, C_, DFF_);
  ln_kernel<0><<<(B_*N_)/4, 256, 0, stream>>>(ypre, ln2_g, ln2_b, outp, nullptr);
}